// Round 14
// baseline (30.441 us; speedup 1.0000x reference)
//
#include <hip/hip_runtime.h>
#include <math.h>

#define NUM_ENTITY 100000
#define NUM_TYPE   5000
#define DIM        128
#define BATCH      512
#define MARGIN     2.0f

#define TG 64       // types per block (one per lane)
#define BB 32       // batch rows per block (8 per wave)
#define BG 8        // batch rows per wave
#define TSTRIDE 68  // t-tile row stride in dwords (64+4; b128 row-reads = 2/bank = free)

typedef _Float16 half_t;
typedef half_t half2_t __attribute__((ext_vector_type(2)));

// r7/r8/r13 all converge at ~26us: shared floor = the per-CU LDS pipe burned
// by WAVE-UNIFORM broadcast ds_read_b128 (128/wave in the inner loop; 16
// useful bytes per ~11cy pipe slot; ~12us/CU serialized, unhideable since
// all 4 SIMDs share it). e-addresses are wave-uniform -> move e to the IDLE
// scalar pipe: pre-pass gathers ent[xb[b]] -> packed f16 in d_ws [512][64]dw;
// main kernel s_loads e rows (readfirstlane forces uniformity), VALU takes
// SGPR src0. Inner loop now has ZERO LDS reads; LDS only stages the t-tile
// (17.4KB -> 9 blocks/CU). launch_bounds min-waves=1 everywhere (session law:
// any min-waves>1 makes hipcc spill: r1/r2/r12).
__device__ __forceinline__ uint32_t pk2(float x, float y) {
    return __builtin_bit_cast(uint32_t, __builtin_amdgcn_cvt_pkrtz(x, y));
}

__device__ __forceinline__ float absdot(uint32_t eu, uint32_t tu, float acc) {
    const half2_t ones = {(half_t)1.0f, (half_t)1.0f};
    half2_t d = __builtin_bit_cast(half2_t, eu) - __builtin_bit_cast(half2_t, tu);
    const uint32_t du = __builtin_bit_cast(uint32_t, d) & 0x7fff7fffu;
#if __has_builtin(__builtin_amdgcn_fdot2)
    return __builtin_amdgcn_fdot2(__builtin_bit_cast(half2_t, du), ones, acc, false);
#else
    half2_t a = __builtin_bit_cast(half2_t, du);
    return acc + (float)a[0] + (float)a[1];
#endif
}

// ---- pre-pass: gather + f32->f16 convert the 512 entity rows into d_ws ----
// ws layout: [BATCH][64] dwords (packed f16 pairs), 131072 B total.
__global__ __launch_bounds__(64, 1) void egather_f16_kernel(
    const float* __restrict__ ent,
    const int*   __restrict__ xb,
    uint32_t*    __restrict__ ws)
{
    const int row = blockIdx.x;            // 0..511
    const int l   = threadIdx.x;           // 0..63
    const int er  = xb[row];
    const float2 v = *(const float2*)&ent[er * DIM + 2 * l];
    ws[row * 64 + l] = pk2(v.x, v.y);
}

// ---- main kernel: t staged in LDS, e via scalar loads from d_ws ----
__global__ __launch_bounds__(256, 1) void l1dist_sigmoid_kernel(
    const float*    __restrict__ typ,
    const uint32_t* __restrict__ ew,    // [BATCH][64] packed f16
    float*          __restrict__ out)
{
    __shared__ uint32_t tL[TG * TSTRIDE];   // 17408 B

    const int tid = threadIdx.x;            // 0..255
    const int l   = tid & 63;               // lane
    const int t0  = blockIdx.x * TG;
    const int b0  = blockIdx.y * BB;

    // ---- stage t tile COALESCED: 64 rows x 32 float4, 8 per thread
#pragma unroll
    for (int s = 0; s < 8; ++s) {
        const int g   = tid + 256 * s;
        const int row = g >> 5;
        const int c4  = g & 31;
        const int tr  = min(t0 + row, NUM_TYPE - 1);
        const float4 v = *(const float4*)&typ[tr * DIM + c4 * 4];
        uint2 pw;
        pw.x = pk2(v.x, v.y);
        pw.y = pk2(v.z, v.w);
        *(uint2*)&tL[row * TSTRIDE + c4 * 2] = pw;
    }
    __syncthreads();

    // ---- own type row LDS -> registers (16 x ds_read_b128, 2/bank = free)
    uint4 tf[16];
#pragma unroll
    for (int c = 0; c < 16; ++c)
        tf[c] = *(const uint4*)&tL[l * TSTRIDE + c * 4];

    const bool valid = (t0 + l) < NUM_TYPE;
    // force wave-index scalarization so e-loads are provably uniform -> s_load
    const int wb = __builtin_amdgcn_readfirstlane((tid >> 6) * BG);

    // ---- compute: 8 b-rows per wave; e row = 64 dwords from scalar pipe
#pragma unroll 1
    for (int i = 0; i < BG; ++i) {
        const int brow = b0 + wb + i;       // wave-uniform
        const uint32_t* er = &ew[brow * 64];
        float acc = 0.0f;
#pragma unroll
        for (int c = 0; c < 16; ++c) {
            const uint4 ev = *(const uint4*)&er[c * 4];   // uniform -> s_load
            acc = absdot(ev.x, tf[c].x, acc);
            acc = absdot(ev.y, tf[c].y, acc);
            acc = absdot(ev.z, tf[c].z, acc);
            acc = absdot(ev.w, tf[c].w, acc);
        }
        if (valid) {
            const float x = MARGIN - acc;
            out[brow * NUM_TYPE + t0 + l] = 1.0f / (1.0f + __expf(-x));
        }
    }
}

// ---- fallback (ws too small): r13 kernel verbatim ----
__global__ __launch_bounds__(256, 1) void l1dist_fallback_kernel(
    const float* __restrict__ ent,
    const float* __restrict__ typ,
    const int*   __restrict__ xb,
    float*       __restrict__ out)
{
    __shared__ uint32_t tL[TG * TSTRIDE];
    __shared__ uint32_t eL[BB * 64];

    const int tid = threadIdx.x;
    const int l   = tid & 63;
    const int w   = tid >> 6;
    const int t0  = blockIdx.x * TG;
    const int b0  = blockIdx.y * BB;

#pragma unroll
    for (int s = 0; s < 4; ++s) {
        const int g = tid + 256 * s;
        const int row = g >> 5, c4 = g & 31;
        const int er = xb[b0 + row];
        const float4 v = *(const float4*)&ent[er * DIM + c4 * 4];
        uint2 pw; pw.x = pk2(v.x, v.y); pw.y = pk2(v.z, v.w);
        *(uint2*)&eL[row * 64 + c4 * 2] = pw;
    }
#pragma unroll
    for (int s = 0; s < 8; ++s) {
        const int g = tid + 256 * s;
        const int row = g >> 5, c4 = g & 31;
        const int tr = min(t0 + row, NUM_TYPE - 1);
        const float4 v = *(const float4*)&typ[tr * DIM + c4 * 4];
        uint2 pw; pw.x = pk2(v.x, v.y); pw.y = pk2(v.z, v.w);
        *(uint2*)&tL[row * TSTRIDE + c4 * 2] = pw;
    }
    __syncthreads();

    uint4 tf[16];
#pragma unroll
    for (int c = 0; c < 16; ++c)
        tf[c] = *(const uint4*)&tL[l * TSTRIDE + c * 4];

    const bool valid = (t0 + l) < NUM_TYPE;
    const int  wb    = w * BG;
#pragma unroll 1
    for (int i = 0; i < BG; ++i) {
        float acc = 0.0f;
#pragma unroll
        for (int c = 0; c < 16; ++c) {
            const uint4 ev = *(const uint4*)&eL[(wb + i) * 64 + c * 4];
            acc = absdot(ev.x, tf[c].x, acc);
            acc = absdot(ev.y, tf[c].y, acc);
            acc = absdot(ev.z, tf[c].z, acc);
            acc = absdot(ev.w, tf[c].w, acc);
        }
        if (valid) {
            const float x = MARGIN - acc;
            out[(b0 + wb + i) * NUM_TYPE + t0 + l] = 1.0f / (1.0f + __expf(-x));
        }
    }
}

extern "C" void kernel_launch(void* const* d_in, const int* in_sizes, int n_in,
                              void* d_out, int out_size, void* d_ws, size_t ws_size,
                              hipStream_t stream) {
    const float* ent = (const float*)d_in[0];
    const float* typ = (const float*)d_in[1];
    const int*   xb  = (const int*)d_in[2];
    float*       out = (float*)d_out;

    const size_t ws_needed = (size_t)BATCH * 64 * sizeof(uint32_t);  // 131072 B
    if (ws_size >= ws_needed) {
        uint32_t* ew = (uint32_t*)d_ws;
        egather_f16_kernel<<<dim3(BATCH), dim3(64), 0, stream>>>(ent, xb, ew);
        dim3 grid((NUM_TYPE + TG - 1) / TG, BATCH / BB);  // (79, 16)
        l1dist_sigmoid_kernel<<<grid, dim3(256), 0, stream>>>(typ, ew, out);
    } else {
        dim3 grid((NUM_TYPE + TG - 1) / TG, BATCH / BB);
        l1dist_fallback_kernel<<<grid, dim3(256), 0, stream>>>(ent, typ, xb, out);
    }
}